// Round 3
// baseline (524.650 us; speedup 1.0000x reference)
//
#include <hip/hip_runtime.h>
#include <float.h>

// Shapes (fixed by the problem)
#define Bsz 2
#define Ssz 4096
#define Hsz 12
#define Gsz 64
#define Wsz 513            // W_LOC
#define Csz (Gsz + Wsz)    // 577 channels
#define ROW (Hsz * Csz)    // 6924 floats per (b,s) row
#define QPR (ROW / 4)      // 1731 float4 quads per row (row base 16B-aligned: 27696 = 1731*16)
#define HALF 256           // (Wsz-1)/2
#define RPB 8              // rows per block -> 1024 blocks, 4/CU, 16 waves/CU
#define WIN (RPB + Wsz - 1) // 520-wide logical window
#define WINP 544           // padded to multiple of 32 for the swizzle

// Workspace layout (floats)
#define PSUM_SZ ((size_t)Bsz * Ssz)   // 8192
#define GACC_SZ ((size_t)Bsz * Gsz)   // 128

// Bank-spread swizzle: bijective within each 32-aligned block.
// Raw scatter addresses are stride-4 across lanes (8-way conflict on 8 banks);
// adding (x>>5) into the low 5 bits staggers each 32-element segment by 1 bank
// -> worst case 2-way (free, m136).
__device__ __forceinline__ int swz(int x) {
    return (x & ~31) | ((x + (x >> 5)) & 31);
}

__device__ __forceinline__ void scatter1(float v, int c, int r,
                                         float* __restrict__ win,
                                         float* __restrict__ gcc) {
    if (c < Gsz) atomicAdd(&gcc[c], v);
    else        atomicAdd(&win[swz(c - Gsz + r)], v);
}

// K1: fused h-sum + anti-diagonal accumulation, max-MLP direct scatter.
// Each thread per row: 7 independent coalesced float4 loads (flat quads
// t+256k), then 28 ds_add_f32 scatters keyed by channel = (4j+e) mod 577
// (bases hoisted out of the row loop). NO barriers inside the row loop:
// cross-row/cross-wave races are handled by the LDS atomics. Latency is
// hidden by 112 B/lane in flight x 16 waves/CU >> BW*latency (~22 KB/CU).
__global__ __launch_bounds__(256) void k1_fused(
    const float* __restrict__ probs, const float* __restrict__ mask,
    float* __restrict__ psum, float* __restrict__ gacc)
{
    __shared__ float win[WINP];    // 2,176 B
    __shared__ float gcc[Gsz];     //   256 B
    const int t = threadIdx.x;
    const int row0 = blockIdx.x * RPB;
    const int b = row0 / Ssz;

    for (int w = t; w < WINP; w += 256) win[w] = 0.f;
    if (t < Gsz) gcc[t] = 0.f;
    __syncthreads();

    // Per-thread channel bases for its 7 quads (same every row; stays in regs).
    int cb[7];
    #pragma unroll
    for (int k = 0; k < 7; ++k) cb[k] = (4 * (t + 256 * k)) % Csz;
    const bool has7 = (t < QPR - 6 * 256);   // t < 195 owns a 7th quad

    for (int r = 0; r < RPB; ++r) {
        const int row = row0 + r;
        const float4* __restrict__ src = (const float4*)(probs + (size_t)row * ROW);
        const float scale = (mask[row] < 0.f) ? 0.f : 1.f;

        // issue all loads up front -> deep MLP
        float4 q0 = src[t];
        float4 q1 = src[t + 256];
        float4 q2 = src[t + 512];
        float4 q3 = src[t + 768];
        float4 q4 = src[t + 1024];
        float4 q5 = src[t + 1280];
        float4 q6 = make_float4(0.f, 0.f, 0.f, 0.f);
        if (has7) q6 = src[t + 1536];

        #define PROC(Q, K) do {                                            \
            int c0 = cb[K];                                                \
            int c1 = c0 + 1; if (c1 >= Csz) c1 -= Csz;                     \
            int c2 = c0 + 2; if (c2 >= Csz) c2 -= Csz;                     \
            int c3 = c0 + 3; if (c3 >= Csz) c3 -= Csz;                     \
            scatter1(Q.x * scale, c0, r, win, gcc);                        \
            scatter1(Q.y * scale, c1, r, win, gcc);                        \
            scatter1(Q.z * scale, c2, r, win, gcc);                        \
            scatter1(Q.w * scale, c3, r, win, gcc);                        \
        } while (0)

        PROC(q0, 0); PROC(q1, 1); PROC(q2, 2);
        PROC(q3, 3); PROC(q4, 4); PROC(q5, 5);
        if (has7) PROC(q6, 6);
        #undef PROC
    }
    __syncthreads();

    // flush the 520-wide window: i = (s0 - 256) + w  (read through the swizzle)
    const int i_base = (row0 - b * Ssz) - HALF;
    for (int w = t; w < WIN; w += 256) {
        const int i = i_base + w;
        if (i >= 0 && i < Ssz) atomicAdd(&psum[b * Ssz + i], win[swz(w)]);
    }
    if (t < Gsz) atomicAdd(&gacc[b * Gsz + t], gcc[t]);
}

// K4: fused scatter + per-batch max + scores + mask.
// grid = B, block = 1024 (16 waves). psum row staged in LDS; the 128-entry
// index-driven scatter is applied to the LDS copy (block b only touches its
// own row), then reduce + write outputs.
__global__ __launch_bounds__(1024) void k4_final(
    const float* __restrict__ psum, const float* __restrict__ thr_p,
    const int* __restrict__ loc_b, const int* __restrict__ loc_i,
    const int* __restrict__ glob_b, const int* __restrict__ glob_i,
    const float* __restrict__ gacc, int n_idx,
    float* __restrict__ out)
{
    const int b = blockIdx.x;
    const int t = threadIdx.x;
    __shared__ float sp[Ssz];      // 16 KB
    const float* p = psum + (size_t)b * Ssz;

    for (int i = t; i < Ssz; i += 1024) sp[i] = p[i];
    __syncthreads();

    // honor the index arrays: psum[loc_b,loc_i] += gacc[glob_b,glob_i]
    for (int k = t; k < n_idx; k += 1024)
        if (loc_b[k] == b)
            atomicAdd(&sp[loc_i[k]], gacc[glob_b[k] * Gsz + glob_i[k]]);
    __syncthreads();

    float m = -FLT_MAX;
    for (int i = t; i < Ssz; i += 1024) m = fmaxf(m, sp[i]);
    #pragma unroll
    for (int off = 32; off >= 1; off >>= 1) m = fmaxf(m, __shfl_down(m, off, 64));

    __shared__ float red[16];
    const int wave = t >> 6, lane = t & 63;
    if (lane == 0) red[wave] = m;
    __syncthreads();
    if (t == 0) {
        float mm = red[0];
        #pragma unroll
        for (int w = 1; w < 16; ++w) mm = fmaxf(mm, red[w]);
        red[0] = mm;
    }
    __syncthreads();
    const float mx = red[0];
    const float thr = fmaxf(1e-5f, thr_p[0]);

    for (int i = t; i < Ssz; i += 1024) {
        float sc = sp[i] / mx;                                    // divide: match ref rounding
        out[(size_t)Bsz * Ssz + (size_t)b * Ssz + i] = sc;        // scores (output 1)
        out[(size_t)b * Ssz + i] = (sc < thr) ? -10000.f : 0.f;   // mask (output 0)
    }
}

extern "C" void kernel_launch(void* const* d_in, const int* in_sizes, int n_in,
                              void* d_out, int out_size, void* d_ws, size_t ws_size,
                              hipStream_t stream)
{
    const float* mask  = (const float*)d_in[0];
    const float* probs = (const float*)d_in[1];
    const float* thr   = (const float*)d_in[2];
    // d_in[3] = max_num_global_attn_indices (hard-coded as Gsz)
    const int* loc_b  = (const int*)d_in[4];
    const int* loc_i  = (const int*)d_in[5];
    const int* glob_b = (const int*)d_in[6];
    const int* glob_i = (const int*)d_in[7];
    const int n_idx = in_sizes[4];

    float* psum = (float*)d_ws;
    float* gacc = psum + PSUM_SZ;
    float* out  = (float*)d_out;

    // zero psum + gacc (ws is poisoned 0xAA before every launch)
    hipMemsetAsync(psum, 0, (PSUM_SZ + GACC_SZ) * sizeof(float), stream);

    k1_fused<<<dim3(Bsz * Ssz / RPB), dim3(256), 0, stream>>>(probs, mask, psum, gacc);
    k4_final<<<dim3(Bsz), dim3(1024), 0, stream>>>(psum, thr, loc_b, loc_i,
                                                   glob_b, glob_i, gacc, n_idx, out);
}

// Round 4
// 334.339 us; speedup vs baseline: 1.5692x; 1.5692x over previous
//
#include <hip/hip_runtime.h>
#include <float.h>

// Shapes (fixed by the problem)
#define Bsz 2
#define Ssz 4096
#define Hsz 12
#define Gsz 64
#define Wsz 513            // W_LOC
#define Csz (Gsz + Wsz)    // 577 channels
#define ROW (Hsz * Csz)    // 6924 floats per (b,s) row
#define HALF 256           // (Wsz-1)/2
#define RPB 8              // rows per block -> 1024 blocks, 4/CU, 16 waves/CU
#define WIN (RPB + Wsz - 1) // 520-wide output window per block

// Workspace layout (floats)
#define PSUM_SZ ((size_t)Bsz * Ssz)   // 8192
#define GACC_SZ ((size_t)Bsz * Gsz)   // 128

// K1: fused h-sum + anti-diagonal accumulation.
// Round-2 ownership structure (thread t owns channels {t, t+256, t+512<577};
// 12-head sum pre-reduced in registers in ascending h order; only 3 LDS
// atomics per thread per row), but with the loads forced into a deep clause:
// all 36 head-values for a row land in statically-indexed register arrays
// before any add, so ~36 coalesced 4B/lane loads are outstanding per wave
// (~9 KB/wave x 16 waves/CU = 145 KB in flight >> ~22 KB BW*latency product).
// Round 2 failed here: accumulate-in-place chains let the compiler shrink to
// VGPR=20 (~8 loads in flight -> 888 GB/s latency-bound).
// NO per-element LDS atomic scatter (round 3's mistake: 28 ds-atomics/thread/
// row put the LDS RMW pipe on the critical path -> 399 GB/s).
__global__ __launch_bounds__(256) void k1_fused(
    const float* __restrict__ probs, const float* __restrict__ mask,
    float* __restrict__ psum, float* __restrict__ gacc)
{
    __shared__ float win[WIN];     // 2,080 B
    const int t = threadIdx.x;
    const int row0 = blockIdx.x * RPB;
    const int b = row0 / Ssz;
    float g = 0.f;                 // thread t<64: global channel t
    const bool c2ok = (t < Csz - 512);   // t <= 64 owns channel t+512

    for (int w = t; w < WIN; w += 256) win[w] = 0.f;
    __syncthreads();

    for (int r = 0; r < RPB; ++r) {
        const int row = row0 + r;
        const float* __restrict__ base = probs + (size_t)row * ROW;
        const float scale = (mask[row] < 0.f) ? 0.f : 1.f;

        // Issue ALL loads for this row before any arithmetic (static-indexed
        // arrays -> registers -> one deep load clause).
        float a[Hsz], bb[Hsz], c[Hsz];
        #pragma unroll
        for (int h = 0; h < Hsz; ++h) {
            const float* __restrict__ hp = base + h * Csz;
            a[h]  = hp[t];                         // channel t
            bb[h] = hp[t + 256];                   // channel t+256
            c[h]  = c2ok ? hp[t + 512] : 0.f;      // channel t+512 (t<65)
        }

        // Ascending-h reduction (matches the earlier bit-exact versions).
        float v0 = 0.f, v1 = 0.f, v2 = 0.f;
        #pragma unroll
        for (int h = 0; h < Hsz; ++h) { v0 += a[h]; v1 += bb[h]; v2 += c[h]; }
        v0 *= scale; v1 *= scale; v2 *= scale;

        if (t < Gsz) g += v0;                                  // global channel
        else atomicAdd(&win[(t - Gsz) + r], v0);               // local, c-64 = t-64
        atomicAdd(&win[(t + 256 - Gsz) + r], v1);              // local, c-64 = t+192
        if (c2ok)
            atomicAdd(&win[(t + 512 - Gsz) + r], v2);          // local, c-64 = t+448
    }
    __syncthreads();

    // flush the 520-wide window: i = (s0 - 256) + w
    const int i_base = (row0 - b * Ssz) - HALF;
    for (int w = t; w < WIN; w += 256) {
        const int i = i_base + w;
        if (i >= 0 && i < Ssz) atomicAdd(&psum[b * Ssz + i], win[w]);
    }
    if (t < Gsz) atomicAdd(&gacc[b * Gsz + t], g);
}

// K4: fused scatter + per-batch max + scores + mask.
// grid = B, block = 1024 (16 waves). psum row staged in LDS; the 128-entry
// index-driven scatter is applied to the LDS copy (block b only touches its
// own row), then reduce + write outputs.
__global__ __launch_bounds__(1024) void k4_final(
    const float* __restrict__ psum, const float* __restrict__ thr_p,
    const int* __restrict__ loc_b, const int* __restrict__ loc_i,
    const int* __restrict__ glob_b, const int* __restrict__ glob_i,
    const float* __restrict__ gacc, int n_idx,
    float* __restrict__ out)
{
    const int b = blockIdx.x;
    const int t = threadIdx.x;
    __shared__ float sp[Ssz];      // 16 KB
    const float* p = psum + (size_t)b * Ssz;

    for (int i = t; i < Ssz; i += 1024) sp[i] = p[i];
    __syncthreads();

    // honor the index arrays: psum[loc_b,loc_i] += gacc[glob_b,glob_i]
    for (int k = t; k < n_idx; k += 1024)
        if (loc_b[k] == b)
            atomicAdd(&sp[loc_i[k]], gacc[glob_b[k] * Gsz + glob_i[k]]);
    __syncthreads();

    float m = -FLT_MAX;
    for (int i = t; i < Ssz; i += 1024) m = fmaxf(m, sp[i]);
    #pragma unroll
    for (int off = 32; off >= 1; off >>= 1) m = fmaxf(m, __shfl_down(m, off, 64));

    __shared__ float red[16];
    const int wave = t >> 6, lane = t & 63;
    if (lane == 0) red[wave] = m;
    __syncthreads();
    if (t == 0) {
        float mm = red[0];
        #pragma unroll
        for (int w = 1; w < 16; ++w) mm = fmaxf(mm, red[w]);
        red[0] = mm;
    }
    __syncthreads();
    const float mx = red[0];
    const float thr = fmaxf(1e-5f, thr_p[0]);

    for (int i = t; i < Ssz; i += 1024) {
        float sc = sp[i] / mx;                                    // divide: match ref rounding
        out[(size_t)Bsz * Ssz + (size_t)b * Ssz + i] = sc;        // scores (output 1)
        out[(size_t)b * Ssz + i] = (sc < thr) ? -10000.f : 0.f;   // mask (output 0)
    }
}

extern "C" void kernel_launch(void* const* d_in, const int* in_sizes, int n_in,
                              void* d_out, int out_size, void* d_ws, size_t ws_size,
                              hipStream_t stream)
{
    const float* mask  = (const float*)d_in[0];
    const float* probs = (const float*)d_in[1];
    const float* thr   = (const float*)d_in[2];
    // d_in[3] = max_num_global_attn_indices (hard-coded as Gsz)
    const int* loc_b  = (const int*)d_in[4];
    const int* loc_i  = (const int*)d_in[5];
    const int* glob_b = (const int*)d_in[6];
    const int* glob_i = (const int*)d_in[7];
    const int n_idx = in_sizes[4];

    float* psum = (float*)d_ws;
    float* gacc = psum + PSUM_SZ;
    float* out  = (float*)d_out;

    // zero psum + gacc (ws is poisoned 0xAA before every launch)
    hipMemsetAsync(psum, 0, (PSUM_SZ + GACC_SZ) * sizeof(float), stream);

    k1_fused<<<dim3(Bsz * Ssz / RPB), dim3(256), 0, stream>>>(probs, mask, psum, gacc);
    k4_final<<<dim3(Bsz), dim3(1024), 0, stream>>>(psum, thr, loc_b, loc_i,
                                                   glob_b, glob_i, gacc, n_idx, out);
}

// Round 6
// 330.794 us; speedup vs baseline: 1.5860x; 1.0107x over previous
//
#include <hip/hip_runtime.h>
#include <float.h>

// Shapes (fixed by the problem)
#define Bsz 2
#define Ssz 4096
#define Hsz 12
#define Gsz 64
#define Wsz 513            // W_LOC
#define Csz (Gsz + Wsz)    // 577 channels
#define ROW (Hsz * Csz)    // 6924 floats per (b,s) row
#define ROWB (ROW * 4)     // 27,696 bytes (16B-aligned: 1731*16)
#define HALF 256           // (Wsz-1)/2
#define RPB 8              // rows per block -> 1024 blocks
#define WIN (RPB + Wsz - 1) // 520-wide output window per block

#define NCHUNK 27          // full 1024B gll chunks per row (27*1024 = 27648)
#define TAILOFF (NCHUNK * 1024) // 48B tail at 27648 (3 lanes x 16B)

// Workspace layout (floats)
#define PSUM_SZ ((size_t)Bsz * Ssz)   // 8192
#define GACC_SZ ((size_t)Bsz * Gsz)   // 128

typedef const __attribute__((address_space(1))) void* gptr_t;
typedef __attribute__((address_space(3))) void* lptr_t;

// Issue one full row (27,696 B) of global->LDS DMA. Every wave issues
// EXACTLY 7 global_load_lds instructions (7 vmcnt events) so the counted
// vmcnt(7) below is uniform:
//   waves 0-2: full chunks {w, w+4, ..., w+24}            (7 chunks)
//   wave 3   : full chunks {3, 7, 11, 15, 19, 23}          (6 chunks)
//              + the 48B tail, exec-masked to lanes 0-2    (1 instr)
// A partially-masked gll still issues once -> one vmcnt event; masked
// lanes write nothing (LDS dest is uniform-base + lane*16 for ACTIVE lanes).
__device__ __forceinline__ void stage_row(const char* rowbase, float* buf,
                                          int wave, int lane)
{
    char* lb = (char*)buf;
    #pragma unroll
    for (int j = 0; j < 7; ++j) {
        const int k = wave + 4 * j;
        if (k < NCHUNK)
            __builtin_amdgcn_global_load_lds(
                (gptr_t)(rowbase + k * 1024 + lane * 16),
                (lptr_t)(lb + k * 1024), 16, 0, 0);
    }
    if (wave == 3 && lane < 3)
        __builtin_amdgcn_global_load_lds(
            (gptr_t)(rowbase + TAILOFF + lane * 16),
            (lptr_t)(lb + TAILOFF), 16, 0, 0);
}

// K1: fused h-sum + anti-diagonal accumulation, gll double-buffer pipeline.
// Rounds 0/1/4 all plateaued at ~97 us (~2.3 TB/s): the HIP scheduler
// re-serializes register-staged loads to ~1-2 in flight per wave no matter
// how the source is written. This version keeps ~7-14 KB of global->LDS DMA
// in flight PER WAVE continuously: stage(next) -> s_waitcnt vmcnt(7)
// (counted, never 0 in steady state) -> raw s_barrier -> LDS compute ->
// raw s_barrier. No __syncthreads in the loop (it would emit vmcnt(0)).
__global__ __launch_bounds__(256) void k1_fused(
    const float* __restrict__ probs, const float* __restrict__ mask,
    float* __restrict__ psum, float* __restrict__ gacc)
{
    __shared__ __align__(16) float bufA[ROW];   // 27,696 B
    __shared__ __align__(16) float bufB[ROW];   // 27,696 B
    __shared__ float win[WIN];                  //  2,080 B
    const int t = threadIdx.x;
    const int wave = t >> 6, lane = t & 63;
    const int row0 = blockIdx.x * RPB;
    const int b = row0 / Ssz;
    float g = 0.f;                 // thread t<64: global channel t
    const bool c2ok = (t < Csz - 512);

    for (int w = t; w < WIN; w += 256) win[w] = 0.f;

    // Preload + pin all mask scales now so the pipelined loop contains ZERO
    // extra vmcnt events (counted waits below must stay exact).
    float sc[RPB];
    #pragma unroll
    for (int r = 0; r < RPB; ++r) {
        sc[r] = (mask[row0 + r] < 0.f) ? 0.f : 1.f;
        asm volatile("" :: "v"(sc[r]));  // force materialization here
    }
    __syncthreads();                     // drains mask loads; covers win init

    const char* pb = (const char*)probs;
    stage_row(pb + (size_t)row0 * ROWB, bufA, wave, lane);   // prologue: 7/wave

    #pragma unroll
    for (int r = 0; r < RPB; ++r) {
        float* cur = (r & 1) ? bufB : bufA;
        float* nxt = (r & 1) ? bufA : bufB;

        if (r + 1 < RPB) {
            stage_row(pb + (size_t)(row0 + r + 1) * ROWB, nxt, wave, lane);
            asm volatile("s_waitcnt vmcnt(7)" ::: "memory"); // row r landed; r+1 in flight
        } else {
            asm volatile("s_waitcnt vmcnt(0)" ::: "memory"); // epilogue drain
        }
        __builtin_amdgcn_sched_barrier(0);
        __builtin_amdgcn_s_barrier();    // raw: no implicit vmcnt(0)

        // h-sum from LDS (round-0 order; lanes read consecutive addrs ->
        // conflict-free). Thread t owns channels {t, t+256, t+512<577}.
        float v0 = 0.f, v1 = 0.f, v2 = 0.f;
        #pragma unroll
        for (int h = 0; h < Hsz; ++h) {
            v0 += cur[h * Csz + t];
            v1 += cur[h * Csz + t + 256];
        }
        if (c2ok) {
            #pragma unroll
            for (int h = 0; h < Hsz; ++h) v2 += cur[h * Csz + t + 512];
        }
        v0 *= sc[r]; v1 *= sc[r]; v2 *= sc[r];

        if (t < Gsz) g += v0;                                  // global channel
        else atomicAdd(&win[(t - Gsz) + r], v0);               // c-64 = t-64
        atomicAdd(&win[(t + 256 - Gsz) + r], v1);              // c-64 = t+192
        if (c2ok)
            atomicAdd(&win[(t + 512 - Gsz) + r], v2);          // c-64 = t+448

        __builtin_amdgcn_s_barrier();    // protect cur before it is restaged
    }
    __syncthreads();

    // flush the 520-wide window: i = (s0 - 256) + w
    const int i_base = (row0 - b * Ssz) - HALF;
    for (int w = t; w < WIN; w += 256) {
        const int i = i_base + w;
        if (i >= 0 && i < Ssz) atomicAdd(&psum[b * Ssz + i], win[w]);
    }
    if (t < Gsz) atomicAdd(&gacc[b * Gsz + t], g);
}

// K4: fused scatter + per-batch max + scores + mask.
// grid = B, block = 1024 (16 waves). psum row staged in LDS; the 128-entry
// index-driven scatter is applied to the LDS copy (block b only touches its
// own row), then reduce + write outputs.
__global__ __launch_bounds__(1024) void k4_final(
    const float* __restrict__ psum, const float* __restrict__ thr_p,
    const int* __restrict__ loc_b, const int* __restrict__ loc_i,
    const int* __restrict__ glob_b, const int* __restrict__ glob_i,
    const float* __restrict__ gacc, int n_idx,
    float* __restrict__ out)
{
    const int b = blockIdx.x;
    const int t = threadIdx.x;
    __shared__ float sp[Ssz];      // 16 KB
    const float* p = psum + (size_t)b * Ssz;

    for (int i = t; i < Ssz; i += 1024) sp[i] = p[i];
    __syncthreads();

    // honor the index arrays: psum[loc_b,loc_i] += gacc[glob_b,glob_i]
    for (int k = t; k < n_idx; k += 1024)
        if (loc_b[k] == b)
            atomicAdd(&sp[loc_i[k]], gacc[glob_b[k] * Gsz + glob_i[k]]);
    __syncthreads();

    float m = -FLT_MAX;
    for (int i = t; i < Ssz; i += 1024) m = fmaxf(m, sp[i]);
    #pragma unroll
    for (int off = 32; off >= 1; off >>= 1) m = fmaxf(m, __shfl_down(m, off, 64));

    __shared__ float red[16];
    const int wave = t >> 6, lane = t & 63;
    if (lane == 0) red[wave] = m;
    __syncthreads();
    if (t == 0) {
        float mm = red[0];
        #pragma unroll
        for (int w = 1; w < 16; ++w) mm = fmaxf(mm, red[w]);
        red[0] = mm;
    }
    __syncthreads();
    const float mx = red[0];
    const float thr = fmaxf(1e-5f, thr_p[0]);

    for (int i = t; i < Ssz; i += 1024) {
        float sc = sp[i] / mx;                                    // divide: match ref rounding
        out[(size_t)Bsz * Ssz + (size_t)b * Ssz + i] = sc;        // scores (output 1)
        out[(size_t)b * Ssz + i] = (sc < thr) ? -10000.f : 0.f;   // mask (output 0)
    }
}

extern "C" void kernel_launch(void* const* d_in, const int* in_sizes, int n_in,
                              void* d_out, int out_size, void* d_ws, size_t ws_size,
                              hipStream_t stream)
{
    const float* mask  = (const float*)d_in[0];
    const float* probs = (const float*)d_in[1];
    const float* thr   = (const float*)d_in[2];
    // d_in[3] = max_num_global_attn_indices (hard-coded as Gsz)
    const int* loc_b  = (const int*)d_in[4];
    const int* loc_i  = (const int*)d_in[5];
    const int* glob_b = (const int*)d_in[6];
    const int* glob_i = (const int*)d_in[7];
    const int n_idx = in_sizes[4];

    float* psum = (float*)d_ws;
    float* gacc = psum + PSUM_SZ;
    float* out  = (float*)d_out;

    // zero psum + gacc (ws is poisoned 0xAA before every launch)
    (void)hipMemsetAsync(psum, 0, (PSUM_SZ + GACC_SZ) * sizeof(float), stream);

    k1_fused<<<dim3(Bsz * Ssz / RPB), dim3(256), 0, stream>>>(probs, mask, psum, gacc);
    k4_final<<<dim3(Bsz), dim3(1024), 0, stream>>>(psum, thr, loc_b, loc_i,
                                                   glob_b, glob_i, gacc, n_idx, out);
}